// Round 2
// baseline (544.441 us; speedup 1.0000x reference)
//
#include <hip/hip_runtime.h>
#include <hip/hip_bf16.h>

#define DIMX  4096
#define KROT  8
#define GRP   128
#define NGG   32
#define NROWS 16384
#define RTILE 128              // rows per task
#define NRT   (NROWS / RTILE)  // 128 row tiles
#define PBLK  16               // blocks per group -> grid 32*16=512, 2 blocks/CU

typedef float f32x4 __attribute__((ext_vector_type(4)));
typedef short s16x8 __attribute__((ext_vector_type(8)));
typedef unsigned short u16;

// ---------------------------------------------------------------------------
// Setup: compose the 8 rotation rounds (+ channel scale) into one 128x128
// matrix per group; emit B = M'^T as bf16 hi/lo in MFMA-fragment-linear order.
// B layout: chunk(g,w,ks,nt,hl) of 64 lanes x 8 bf16 (16B/lane, coalesced).
// ---------------------------------------------------------------------------
__global__ __launch_bounds__(512) void compose(const float* __restrict__ theta,
                                               const int*   __restrict__ pairs,
                                               const float* __restrict__ scales,
                                               u16* __restrict__ B) {
    __shared__ float M[GRP * GRP];           // M[r*128 + d]
    const int g = blockIdx.x;
    const int tid = threadIdx.x;
    const int j = tid & 127, q = tid >> 7;   // column j, rotation-slice q

    for (int r = q * 32; r < q * 32 + 32; ++r) M[r * GRP + j] = (r == j) ? 1.f : 0.f;
    __syncthreads();

    for (int k = 0; k < KROT; ++k) {
        for (int t = 0; t < 16; ++t) {       // rotations within a round are disjoint
            int tp = q * 16 + t;
            int ie = pairs[k * DIMX + g * GRP + 2 * tp];
            int io = pairs[k * DIMX + g * GRP + 2 * tp + 1];
            float ang = theta[k * (DIMX / 2) + g * 64 + tp];
            float c = cosf(ang), s = sinf(ang);
            float a = M[ie * GRP + j], b = M[io * GRP + j];
            M[ie * GRP + j] = a * c - b * s;
            M[io * GRP + j] = a * s + b * c;
        }
        __syncthreads();
    }

    // B[d][c] = scale[c] * M[c][d], split bf16 hi/lo, fragment-linear.
    const int l = tid & 63, nt = (tid >> 6) & 1, ks = (tid >> 7) & 3;
    for (int w = 0; w < 4; ++w) {
        int c = w * 32 + nt * 16 + (l & 15);
        float sc = scales[g * GRP + c];
        int dbase = ks * 32 + ((l >> 4) & 3) * 8;     // kappa(l, e=0)
        s16x8 vh, vl;
        #pragma unroll
        for (int e = 0; e < 8; ++e) {
            float v = sc * M[c * GRP + dbase + e];
            __hip_bfloat16 h = __float2bfloat16(v);
            float r = v - __bfloat162float(h);
            __hip_bfloat16 lo = __float2bfloat16(r);
            vh[e] = (short)*(u16*)&h;
            vl[e] = (short)*(u16*)&lo;
        }
        int off = (((g * 4 + w) * 4 + ks) * 2 + nt) * 2;
        *(s16x8*)(B + (size_t)(off + 0) * 512 + l * 8) = vh;
        *(s16x8*)(B + (size_t)(off + 1) * 512 + l * 8) = vl;
    }
}

// ---------------------------------------------------------------------------
// Main: batched GEMM  out[n, g*128+c] = sum_d x[n, g*128+d] * B_g[d][c]
// Block = one group, loops row tiles. 4 waves x 32 cols; B frags in regs.
// A tile f32 in LDS via global_load_lds (XOR-swizzled source), converted to
// bf16 hi/lo at fragment-read time. 3-term MFMA for ~f32 precision.
// ---------------------------------------------------------------------------
__global__ __launch_bounds__(256, 2) void rot_gemm(const float* __restrict__ x,
                                                   const u16* __restrict__ B,
                                                   float* __restrict__ out) {
    __shared__ float At[RTILE * GRP];        // 64 KiB, 16B-block-swizzled
    const int tid = threadIdx.x;
    const int l = tid & 63, wv = tid >> 6;
    const int g = blockIdx.x >> 4;
    const int p = blockIdx.x & (PBLK - 1);

    // B fragments: loaded once per block (L2-hot, 2 MB table)
    s16x8 bh[4][2], bl[4][2];
    #pragma unroll
    for (int ks = 0; ks < 4; ++ks)
        #pragma unroll
        for (int nt = 0; nt < 2; ++nt) {
            int off = (((g * 4 + wv) * 4 + ks) * 2 + nt) * 2;
            bh[ks][nt] = *(const s16x8*)(B + (size_t)(off + 0) * 512 + l * 8);
            bl[ks][nt] = *(const s16x8*)(B + (size_t)(off + 1) * 512 + l * 8);
        }

    for (int t = p; t < NRT; t += PBLK) {
        const float* xb = x + (size_t)t * RTILE * DIMX + g * GRP;

        // stage A: lds[row][b] = global[row][b ^ (row&7)]  (16B blocks)
        // XOR stays within a 128B line -> coalesced; read undoes the XOR.
        #pragma unroll
        for (int i = 0; i < 16; ++i) {
            int Lb = i * 256 + tid;
            int row = Lb >> 5, blk = Lb & 31;
            const float* src = xb + (size_t)row * DIMX + ((blk ^ (row & 7)) * 4);
            float* dst = &At[(i * 256 + wv * 64) * 4];   // wave-uniform base
            __builtin_amdgcn_global_load_lds(
                (const __attribute__((address_space(1))) void*)src,
                (__attribute__((address_space(3))) void*)dst, 16, 0, 0);
        }
        __syncthreads();

        f32x4 acc[8][2] = {};
        #pragma unroll
        for (int ks = 0; ks < 4; ++ks) {
            #pragma unroll
            for (int m = 0; m < 8; ++m) {
                int row = m * 16 + (l & 15);
                int bb = ks * 8 + ((l >> 4) & 3) * 2;
                const f32x4* lp = (const f32x4*)At;
                f32x4 a0 = lp[row * 32 + ((bb)     ^ (row & 7))];
                f32x4 a1 = lp[row * 32 + ((bb + 1) ^ (row & 7))];
                s16x8 ah, al;
                #pragma unroll
                for (int e = 0; e < 8; ++e) {
                    float v = (e < 4) ? a0[e] : a1[e - 4];
                    __hip_bfloat16 h = __float2bfloat16(v);
                    float rr = v - __bfloat162float(h);
                    __hip_bfloat16 lo = __float2bfloat16(rr);
                    ah[e] = (short)*(u16*)&h;
                    al[e] = (short)*(u16*)&lo;
                }
                #pragma unroll
                for (int nt = 0; nt < 2; ++nt) {
                    acc[m][nt] = __builtin_amdgcn_mfma_f32_16x16x32_bf16(ah, bh[ks][nt], acc[m][nt], 0, 0, 0);
                    acc[m][nt] = __builtin_amdgcn_mfma_f32_16x16x32_bf16(ah, bl[ks][nt], acc[m][nt], 0, 0, 0);
                    acc[m][nt] = __builtin_amdgcn_mfma_f32_16x16x32_bf16(al, bh[ks][nt], acc[m][nt], 0, 0, 0);
                }
            }
        }
        __syncthreads();   // LDS reads done before next task's stage

        // C/D layout (m89-verified): col = lane&15, row = (lane>>4)*4 + reg
        float* ob = out + (size_t)t * RTILE * DIMX + g * GRP + wv * 32;
        #pragma unroll
        for (int m = 0; m < 8; ++m)
            #pragma unroll
            for (int nt = 0; nt < 2; ++nt)
                #pragma unroll
                for (int i = 0; i < 4; ++i) {
                    int row = m * 16 + ((l >> 4) & 3) * 4 + i;
                    ob[(size_t)row * DIMX + nt * 16 + (l & 15)] = acc[m][nt][i];
                }
    }
}

extern "C" void kernel_launch(void* const* d_in, const int* in_sizes, int n_in,
                              void* d_out, int out_size, void* d_ws, size_t ws_size,
                              hipStream_t stream) {
    const float* xin    = (const float*)d_in[0];
    const int*   pairs  = (const int*)d_in[1];
    const float* theta  = (const float*)d_in[2];
    const float* scales = (const float*)d_in[3];
    float* outp = (float*)d_out;
    u16*   Btab = (u16*)d_ws;                 // 2 MiB

    compose<<<NGG, 512, 0, stream>>>(theta, pairs, scales, Btab);
    rot_gemm<<<NGG * PBLK, 256, 0, stream>>>(xin, Btab, outp);
}

// Round 7
// 508.235 us; speedup vs baseline: 1.0712x; 1.0712x over previous
//
#include <hip/hip_runtime.h>
#include <hip/hip_bf16.h>

#define DIMX  4096
#define KROT  8
#define GRP   128
#define NGG   32
#define NROWS 16384
#define RT2   64                   // rows per task
#define NT2   (NROWS / RT2)        // 256 row tiles
#define GPG   24                   // row-tile strides per group
#define GRID2 (NGG * GPG)          // 768 blocks = 3/CU

typedef float f32x4 __attribute__((ext_vector_type(4)));
typedef short s16x8 __attribute__((ext_vector_type(8)));
typedef unsigned short u16;

// ---------------------------------------------------------------------------
// Compose the 8 rotation rounds (+ channel scale) into one 128x128 matrix per
// group; emit B = M'^T as bf16 hi/lo in MFMA-fragment-linear order.
// Chunk(g,w,ks,nt,hl): 64 lanes x 8 bf16, 16B/lane. (Verified in R2.)
// ---------------------------------------------------------------------------
__global__ __launch_bounds__(512) void compose(const float* __restrict__ theta,
                                               const int*   __restrict__ pairs,
                                               const float* __restrict__ scales,
                                               u16* __restrict__ B) {
    __shared__ float M[GRP * GRP];           // M[r*128 + d]
    const int g = blockIdx.x;
    const int tid = threadIdx.x;
    const int j = tid & 127, q = tid >> 7;

    for (int r = q * 32; r < q * 32 + 32; ++r) M[r * GRP + j] = (r == j) ? 1.f : 0.f;
    __syncthreads();

    for (int k = 0; k < KROT; ++k) {
        for (int t = 0; t < 16; ++t) {
            int tp = q * 16 + t;
            int ie = pairs[k * DIMX + g * GRP + 2 * tp];
            int io = pairs[k * DIMX + g * GRP + 2 * tp + 1];
            float ang = theta[k * (DIMX / 2) + g * 64 + tp];
            float c = cosf(ang), s = sinf(ang);
            float a = M[ie * GRP + j], b = M[io * GRP + j];
            M[ie * GRP + j] = a * c - b * s;
            M[io * GRP + j] = a * s + b * c;
        }
        __syncthreads();
    }

    const int l = tid & 63, nt = (tid >> 6) & 1, ks = (tid >> 7) & 3;
    for (int w = 0; w < 4; ++w) {
        int c = w * 32 + nt * 16 + (l & 15);
        float sc = scales[g * GRP + c];
        int dbase = ks * 32 + ((l >> 4) & 3) * 8;
        s16x8 vh, vl;
        #pragma unroll
        for (int e = 0; e < 8; ++e) {
            float v = sc * M[c * GRP + dbase + e];
            __hip_bfloat16 h = __float2bfloat16(v);
            float r = v - __bfloat162float(h);
            __hip_bfloat16 lo = __float2bfloat16(r);
            vh[e] = (short)*(u16*)&h;
            vl[e] = (short)*(u16*)&lo;
        }
        int off = (((g * 4 + w) * 4 + ks) * 2 + nt) * 2;
        *(s16x8*)(B + (size_t)(off + 0) * 512 + l * 8) = vh;
        *(s16x8*)(B + (size_t)(off + 1) * 512 + l * 8) = vl;
    }
}

// ---------------------------------------------------------------------------
// Main: out[n, g*128+c] = sum_d x[n, g*128+d] * B_g[d][c]
// A: direct global->VGPR (16 rows x 64B segments/inst), no LDS, no barriers
// in the compute phase. Truncation hi / RNE lo split, 3-term bf16 MFMA.
// C: acc -> swizzled LDS (2-way writes) -> coalesced dwordx4 stores.
// ---------------------------------------------------------------------------
__global__ __launch_bounds__(256, 3) void rot_gemm(const float* __restrict__ x,
                                                   const u16* __restrict__ B,
                                                   float* __restrict__ out) {
    __shared__ __align__(16) float C[RT2 * GRP];   // 32 KiB transpose buffer
    const int tid = threadIdx.x;
    const int l  = tid & 63, wv = tid >> 6;
    const int lr = l & 15;          // fragment row within a 16-row strip
    const int lq = (l >> 4) & 3;    // k-quad within a 32-elem k-slice
    const int g  = blockIdx.x & 31; // group fixed per block -> B loaded once

    // B fragments: hi/lo, this wave's 32-col slice, all 4 k-slices
    s16x8 bh[4][2], bl[4][2];
    #pragma unroll
    for (int ks = 0; ks < 4; ++ks)
        #pragma unroll
        for (int nt = 0; nt < 2; ++nt) {
            int off = (((g * 4 + wv) * 4 + ks) * 2 + nt) * 2;
            bh[ks][nt] = *(const s16x8*)(B + (size_t)(off + 0) * 512 + l * 8);
            bl[ks][nt] = *(const s16x8*)(B + (size_t)(off + 1) * 512 + l * 8);
        }

    for (int rt = blockIdx.x >> 5; rt < NT2; rt += GPG) {
        const float* xt = x + (size_t)(rt * RT2) * DIMX + g * GRP;
        f32x4 acc[4][2] = {};

        #pragma unroll 1                       // keep VGPR: strip-granular loads
        for (int m = 0; m < 4; ++m) {
            f32x4 a0[4], a1[4];
            #pragma unroll
            for (int ks = 0; ks < 4; ++ks) {   // 8 loads in flight per strip
                const float* p = xt + (size_t)(m * 16 + lr) * DIMX + ks * 32 + lq * 8;
                a0[ks] = *(const f32x4*)p;
                a1[ks] = *(const f32x4*)(p + 4);
            }
            #pragma unroll
            for (int ks = 0; ks < 4; ++ks) {
                s16x8 ah, al;
                #pragma unroll
                for (int e = 0; e < 8; ++e) {
                    float v = (e < 4) ? a0[ks][e] : a1[ks][e - 4];
                    unsigned u = __builtin_bit_cast(unsigned, v);
                    ah[e] = (short)(u >> 16);                    // truncation hi
                    float r = v - __builtin_bit_cast(float, u & 0xffff0000u);
                    __hip_bfloat16 lo = __float2bfloat16(r);     // exact-residual lo
                    al[e] = (short)*(u16*)&lo;
                }
                #pragma unroll
                for (int nt = 0; nt < 2; ++nt) {
                    acc[m][nt] = __builtin_amdgcn_mfma_f32_16x16x32_bf16(ah, bh[ks][nt], acc[m][nt], 0, 0, 0);
                    acc[m][nt] = __builtin_amdgcn_mfma_f32_16x16x32_bf16(ah, bl[ks][nt], acc[m][nt], 0, 0, 0);
                    acc[m][nt] = __builtin_amdgcn_mfma_f32_16x16x32_bf16(al, bh[ks][nt], acc[m][nt], 0, 0, 0);
                }
            }
        }

        // acc -> LDS, col XOR-swizzled by (row&12)<<2: ds_write 2-way (free)
        #pragma unroll
        for (int m = 0; m < 4; ++m)
            #pragma unroll
            for (int nt = 0; nt < 2; ++nt)
                #pragma unroll
                for (int i = 0; i < 4; ++i) {
                    int row = m * 16 + lq * 4 + i;
                    int col = wv * 32 + nt * 16 + lr;
                    C[row * GRP + (col ^ ((row & 12) << 2))] = acc[m][nt][i];
                }
        __syncthreads();

        // coalesced store: 32 lanes x float4 = full 512B rows
        float* ob = out + (size_t)(rt * RT2) * DIMX + g * GRP;
        #pragma unroll
        for (int j = 0; j < 8; ++j) {
            int flat = j * 256 + tid;
            int row = flat >> 5, c4 = (flat & 31) * 4;
            f32x4 v = *(const f32x4*)&C[row * GRP + (c4 ^ ((row & 12) << 2))];
            *(f32x4*)(ob + (size_t)row * DIMX + c4) = v;
        }
        __syncthreads();   // LDS reuse guard for next tile
    }
}

extern "C" void kernel_launch(void* const* d_in, const int* in_sizes, int n_in,
                              void* d_out, int out_size, void* d_ws, size_t ws_size,
                              hipStream_t stream) {
    const float* xin    = (const float*)d_in[0];
    const int*   pairs  = (const int*)d_in[1];
    const float* theta  = (const float*)d_in[2];
    const float* scales = (const float*)d_in[3];
    float* outp = (float*)d_out;
    u16*   Btab = (u16*)d_ws;                 // 2 MiB fragment table

    compose<<<NGG, 512, 0, stream>>>(theta, pairs, scales, Btab);
    rot_gemm<<<GRID2, 256, 0, stream>>>(xin, Btab, outp);
}